// Round 13
// baseline (1294.331 us; speedup 1.0000x reference)
//
#include <hip/hip_runtime.h>
#include <stdint.h>

#define T_ROWS 256
#define KF 4096
#define OF 11008
// grouped (dest) segment layout: [0,3712) 4-bit, [3712,3968) 6-bit, [3968,4096) 8-bit

typedef int   v4i __attribute__((ext_vector_type(4)));
typedef float v4f __attribute__((ext_vector_type(4)));

typedef const __attribute__((address_space(1))) uint8_t* gptr_t;
typedef __attribute__((address_space(3))) uint8_t* lptr_t;

// ---------------------------------------------------------------------------
// Kernel 1: FUSED perm + quantize. ctrl[0]=claim, ctrl[1]=ready (memset to 0
// each call). Every block: (spinners) stage own row -> spin; (winner: first
// block to CAS) run perm body in LDS-union -> threadfence+publish -> stage.
// Per-row quant body is byte-identical to R8 (79.1 us, verified).
// ---------------------------------------------------------------------------
__global__ __launch_bounds__(256) void quantperm_k(const float* __restrict__ x,
                                                   const float* __restrict__ W,
                                                   const int* __restrict__ idx,
                                                   int* __restrict__ src_of,
                                                   int* __restrict__ ctrl,
                                                   int8_t* __restrict__ qX,
                                                   int8_t* __restrict__ qW,
                                                   float* __restrict__ sX,
                                                   float* __restrict__ sW) {
    __shared__ union {
        float rowbuf[KF];                                  // 16 KB (quant)
        struct { uint8_t g[KF]; int cnt[3][256]; int exc[3][256]; } p;  // 10.2 KB (perm)
    } u;
    __shared__ float lmax[256];
    __shared__ float sm[3];
    __shared__ int role;

    const int b = blockIdx.x;
    const int t = threadIdx.x;
    const int w = t >> 6, ln = t & 63;
    const float* src; int8_t* qout; float* scales; int r; int nrows;
    if (b < T_ROWS) { src = x; qout = qX; scales = sX; r = b; nrows = T_ROWS; }
    else           { src = W; qout = qW; scales = sW; r = b - T_ROWS; nrows = OF; }
    const float* row = src + (size_t)r * KF;

    auto stage = [&]() {
#pragma unroll
        for (int j = 0; j < 4; ++j) {
            const uint8_t* srcp = (const uint8_t*)(row + j * 1024 + t * 4);
            __builtin_amdgcn_global_load_lds((gptr_t)srcp, (lptr_t)&u.rowbuf[j * 1024 + w * 256], 16, 0, 0);
        }
    };

    if (t == 0) role = (atomicCAS(&ctrl[0], 0, 1) == 0) ? 1 : 0;
    __syncthreads();

    if (role) {
        // ---- perm body (R8-verified), LDS-union region ----
        for (int i = 0; i < 16; ++i) {
            int p = t * 16 + i;
            int seg = p < 3712 ? 0 : (p < 3968 ? 1 : 2);
            u.p.g[idx[p]] = (uint8_t)seg;
        }
        __syncthreads();
        int c0 = 0, c1 = 0, c2 = 0;
        for (int i = 0; i < 16; ++i) {
            int s = u.p.g[t * 16 + i];
            c0 += (s == 0); c1 += (s == 1); c2 += (s == 2);
        }
        u.p.cnt[0][t] = c0; u.p.cnt[1][t] = c1; u.p.cnt[2][t] = c2;
        __syncthreads();
        if (t < 192) {
            int s = t >> 6, l = t & 63;
            int run = 0;
            for (int j = 0; j < 4; ++j) {
                int xx = u.p.cnt[s][j * 64 + l];
                int inc = xx;
#pragma unroll
                for (int off = 1; off < 64; off <<= 1) {
                    int y = __shfl_up(inc, off);
                    if (l >= off) inc += y;
                }
                u.p.exc[s][j * 64 + l] = run + inc - xx;
                run += __shfl(inc, 63);
            }
        }
        __syncthreads();
        int off0 = u.p.exc[0][t], off1 = 3712 + u.p.exc[1][t], off2 = 3968 + u.p.exc[2][t];
        for (int i = 0; i < 16; ++i) {
            int c = t * 16 + i;
            int s = u.p.g[c];
            int d = (s == 0) ? off0++ : (s == 1) ? off1++ : off2++;
            src_of[d] = c;
        }
        __syncthreads();
        __threadfence();                              // flush src_of to device scope
        if (t == 0) atomicExch(&ctrl[1], 1);          // publish
        stage();                                      // stage own row (after union use)
    } else {
        stage();                                      // overlap HBM with perm
        if (t == 0) {
            while (atomicAdd(&ctrl[1], 0) == 0) __builtin_amdgcn_s_sleep(2);
        }
        __syncthreads();
        __threadfence();                              // acquire: invalidate caches
    }

    // ---- R8 quant body (verified) ----
    const int seg = t < 232 ? 0 : (t < 248 ? 1 : 2);
    const float qmax = seg == 0 ? 7.f : (seg == 1 ? 31.f : 127.f);
    int c[16];
#pragma unroll
    for (int i = 0; i < 4; ++i) {
        v4i ci = *(const v4i*)&src_of[t * 16 + i * 4];
        c[i*4+0] = ci[0]; c[i*4+1] = ci[1]; c[i*4+2] = ci[2]; c[i*4+3] = ci[3];
    }
    asm volatile("s_waitcnt vmcnt(0)" ::: "memory");
    __syncthreads();

    float v[16];
    float mx = 0.f;
#pragma unroll
    for (int i = 0; i < 16; ++i) { v[i] = u.rowbuf[c[i]]; mx = fmaxf(mx, fabsf(v[i])); }
    lmax[t] = mx;
    __syncthreads();
    if (w == 0) {
        float m = fmaxf(fmaxf(lmax[ln], lmax[ln + 64]), lmax[ln + 128]);
        if (ln < 40) m = fmaxf(m, lmax[ln + 192]);
#pragma unroll
        for (int off = 32; off; off >>= 1) m = fmaxf(m, __shfl_xor(m, off));
        if (ln == 0) sm[0] = m;
    } else if (w == 1) {
        float m = ln < 16 ? lmax[232 + ln] : 0.f;
#pragma unroll
        for (int off = 8; off; off >>= 1) m = fmaxf(m, __shfl_xor(m, off));
        if (ln == 0) sm[1] = m;
    } else if (w == 2) {
        float m = ln < 8 ? lmax[248 + ln] : 0.f;
#pragma unroll
        for (int off = 4; off; off >>= 1) m = fmaxf(m, __shfl_xor(m, off));
        if (ln == 0) sm[2] = m;
    }
    __syncthreads();
    float s = sm[seg] / qmax;
    if (s == 0.f) s = 1.f;
    if (t == 0 || t == 232 || t == 248) scales[seg * nrows + r] = s;
    const float rs = 1.0f / s;
    union { int8_t bb[16]; v4i q; } uq;
#pragma unroll
    for (int i = 0; i < 16; ++i) {
        float qv = rintf(fminf(fmaxf(v[i] * rs, -qmax), qmax));  // RNE == np.round
        uq.bb[i] = (int8_t)qv;
    }
    *(v4i*)(qout + (size_t)r * KF + t * 16) = uq.q;
}

// ---------------------------------------------------------------------------
// Kernel 2 (R5-verified, byte-identical): int8 MFMA GEMM, 128x64 tile,
// grid 344, 4 waves. BK=128, 32 steps.
// ---------------------------------------------------------------------------
__global__ __launch_bounds__(256, 2)
void gemm_k(const int8_t* __restrict__ qX, const int8_t* __restrict__ qW,
            const float* __restrict__ sX, const float* __restrict__ sW,
            const float* __restrict__ bias, float* __restrict__ out) {
    __shared__ __align__(16) int8_t lB[3][64 * 128];

    const int bid = blockIdx.x;
    const int swz = (bid & 7) * 43 + (bid >> 3);  // 344 = 8*43: bijective
    const int row0 = (swz & 1) * 128;
    const int col0 = (swz >> 1) * 64;
    const int tid = threadIdx.x;
    const int lane = tid & 63;
    const int w = tid >> 6;
    const int lr = lane >> 3, lc = lane & 7;
    const int kg = lane >> 4;     // 0..3: K-chunk group
    const int cr = lane & 15;     // row/col within fragment

    v4i iacc[2][4];
    v4f facc[2][4];
#pragma unroll
    for (int m = 0; m < 2; ++m)
#pragma unroll
        for (int n = 0; n < 4; ++n) {
            iacc[m][n][0]=0; iacc[m][n][1]=0; iacc[m][n][2]=0; iacc[m][n][3]=0;
            facc[m][n][0]=0.f; facc[m][n][1]=0.f; facc[m][n][2]=0.f; facc[m][n][3]=0.f;
        }

    const int8_t* aRow[2];
    aRow[0] = qX + (size_t)(row0 + w * 32 + cr) * KF;
    aRow[1] = qX + (size_t)(row0 + w * 32 + 16 + cr) * KF;

    auto stageB = [&](int slot, int step) {
        const int k0 = step * 128;
        const int sc = (lc ^ lr) << 4;            // pre-swizzled source chunk
#pragma unroll
        for (int j = 0; j < 2; ++j) {
            const int brow = j * 32 + w * 8;      // +lr comes from lane offset
            const uint8_t* src = (const uint8_t*)qW + (size_t)(col0 + brow + lr) * KF + k0 + sc;
            __builtin_amdgcn_global_load_lds((gptr_t)src, (lptr_t)&lB[slot][brow * 128], 16, 0, 0);
        }
    };

    auto loadA = [&](v4i (&a)[2][2], int step) {
        const int kb = step * 128 + kg * 16;
#pragma unroll
        for (int m = 0; m < 2; ++m)
#pragma unroll
            for (int kk = 0; kk < 2; ++kk) {
                const int8_t* p = aRow[m] + kb + kk * 64;
                asm volatile("global_load_dwordx4 %0, %1, off"
                             : "=v"(a[m][kk]) : "v"(p) : "memory");
            }
    };

    auto flush = [&](int seg) {
#pragma unroll
        for (int m = 0; m < 2; ++m) {
            float sa[4];
#pragma unroll
            for (int rr = 0; rr < 4; ++rr)
                sa[rr] = sX[seg * T_ROWS + row0 + w * 32 + m * 16 + ((lane >> 4) << 2) + rr];
#pragma unroll
            for (int n = 0; n < 4; ++n) {
                const float sb = sW[seg * OF + col0 + n * 16 + (lane & 15)];
#pragma unroll
                for (int rr = 0; rr < 4; ++rr) {
                    facc[m][n][rr] += (float)iacc[m][n][rr] * (sa[rr] * sb);
                    iacc[m][n][rr] = 0;
                }
            }
        }
    };

    auto body = [&](int t, v4i (&aCur)[2][2], v4i (&aNext)[2][2]) {
        __builtin_amdgcn_s_barrier();
        // B fragments from LDS (lgkm-tracked)
        v4i bf[4][2];
        const int8_t* pb = &lB[t % 3][0];
#pragma unroll
        for (int n = 0; n < 4; ++n) {
            const int brow = n * 16 + cr;
#pragma unroll
            for (int kk = 0; kk < 2; ++kk) {
                const int ch = (kk * 4 + kg) ^ (brow & 7);
                bf[n][kk] = *(const v4i*)(pb + brow * 128 + ch * 16);
            }
        }
        // issue next prefetches (stay in flight across the wait)
        if (t + 2 < 32) stageB((t + 2) % 3, t + 2);
        if (t + 1 < 32) loadA(aNext, t + 1);
        // single wait point: aCur + B(t+1) retired; 6 newest stay in flight
        if (t < 30)       asm volatile("s_waitcnt vmcnt(6) lgkmcnt(0)" ::: "memory");
        else if (t == 30) asm volatile("s_waitcnt vmcnt(4) lgkmcnt(0)" ::: "memory");
        else              asm volatile("s_waitcnt vmcnt(0) lgkmcnt(0)" ::: "memory");
        __builtin_amdgcn_sched_barrier(0);
#pragma unroll
        for (int kk = 0; kk < 2; ++kk)
#pragma unroll
            for (int m = 0; m < 2; ++m)
#pragma unroll
                for (int n = 0; n < 4; ++n)
                    iacc[m][n] = __builtin_amdgcn_mfma_i32_16x16x64_i8(aCur[m][kk], bf[n][kk], iacc[m][n], 0, 0, 0);
        if (t == 28) flush(0);          // seg0: K [0,3712)
        else if (t == 30) flush(1);     // seg1: K [3712,3968)
    };

    v4i aA[2][2], aB[2][2];
    stageB(0, 0);
    stageB(1, 1);
    loadA(aA, 0);
    asm volatile("s_waitcnt vmcnt(6)" ::: "memory");   // B(0) landed

    for (int tt = 0; tt < 32; tt += 2) {
        body(tt,     aA, aB);
        body(tt + 1, aB, aA);
    }
    flush(2);                           // seg2: K [3968,4096)

#pragma unroll
    for (int m = 0; m < 2; ++m)
#pragma unroll
        for (int n = 0; n < 4; ++n) {
            const int colg = col0 + n * 16 + (lane & 15);
            const float bv = bias[colg];
#pragma unroll
            for (int rr = 0; rr < 4; ++rr) {
                const int rowg = row0 + w * 32 + m * 16 + ((lane >> 4) << 2) + rr;
                out[(size_t)rowg * OF + colg] = facc[m][n][rr] + bv;
            }
        }
}

// ---------------------------------------------------------------------------
// workspace layout (bytes):
//   qX     @ 0          :  1,048,576
//   qW     @ 1,048,576  : 45,088,768
//   sX     @ 46,137,344 :      3,072
//   sW     @ 46,140,416 :    132,096
//   src_of @ 46,272,512 :     16,384
//   ctrl   @ 46,288,896 :         16   (memset to 0 each call)
// ---------------------------------------------------------------------------
extern "C" void kernel_launch(void* const* d_in, const int* in_sizes, int n_in,
                              void* d_out, int out_size, void* d_ws, size_t ws_size,
                              hipStream_t stream) {
    const float* x    = (const float*)d_in[0];
    const float* W    = (const float*)d_in[1];
    const float* bias = (const float*)d_in[2];
    const int*   ridx = (const int*)d_in[3];
    float* out = (float*)d_out;

    uint8_t* ws = (uint8_t*)d_ws;
    int8_t* qX = (int8_t*)ws;
    int8_t* qW = (int8_t*)(ws + 1048576);
    float*  sX = (float*)(ws + 46137344);
    float*  sW = (float*)(ws + 46140416);
    int* src_of = (int*)(ws + 46272512);
    int* ctrl   = (int*)(ws + 46288896);

    hipMemsetAsync(ctrl, 0, 16, stream);
    quantperm_k<<<T_ROWS + OF, 256, 0, stream>>>(x, W, ridx, src_of, ctrl, qX, qW, sX, sW);
    gemm_k<<<344, 256, 0, stream>>>(qX, qW, sX, sW, bias, out);
}

// Round 14
// 74.260 us; speedup vs baseline: 17.4298x; 17.4298x over previous
//
#include <hip/hip_runtime.h>
#include <stdint.h>

#define T_ROWS 256
#define KF 4096
#define OF 11008
// grouped (dest) layout d = permuted position: [0,3712) 4-bit, [3712,3968) 6-bit,
// [3968,4096) 8-bit. Source column for dest d is simply idx[d] (within-segment
// order = permuted order; order is free for dot products, maxes, and scales).

typedef int   v4i __attribute__((ext_vector_type(4)));
typedef float v4f __attribute__((ext_vector_type(4)));

typedef const __attribute__((address_space(1))) uint8_t* gptr_t;
typedef __attribute__((address_space(3))) uint8_t* lptr_t;

// ---------------------------------------------------------------------------
// Kernel 1 (R8-verified body; src_of := idx): per-row quantize. One block per
// row. Row staged to LDS via global_load_lds (16B, wave-uniform dest);
// permutation gather resolved in LDS; one divide per thread (rs = 1/s).
// Thread t owns dest [t*16, t*16+16) — single segment each
// (3712 = 232*16, 256 = 16*16, 128 = 8*16).
// ---------------------------------------------------------------------------
__global__ __launch_bounds__(256) void quant_k(const float* __restrict__ x,
                                               const float* __restrict__ W,
                                               const int* __restrict__ idx,
                                               int8_t* __restrict__ qX,
                                               int8_t* __restrict__ qW,
                                               float* __restrict__ sX,
                                               float* __restrict__ sW) {
    __shared__ float rowbuf[KF];
    __shared__ float lmax[256];
    __shared__ float sm[3];
    const int b = blockIdx.x;
    const int t = threadIdx.x;
    const int w = t >> 6, ln = t & 63;
    const float* src; int8_t* qout; float* scales; int r; int nrows;
    if (b < T_ROWS) { src = x; qout = qX; scales = sX; r = b; nrows = T_ROWS; }
    else           { src = W; qout = qW; scales = sW; r = b - T_ROWS; nrows = OF; }
    const float* row = src + (size_t)r * KF;

    // async stage 16 KB: 4 x 16B per thread, wave-uniform LDS base + lane*16
#pragma unroll
    for (int j = 0; j < 4; ++j) {
        const uint8_t* srcp = (const uint8_t*)(row + j * 1024 + t * 4);
        __builtin_amdgcn_global_load_lds((gptr_t)srcp, (lptr_t)&rowbuf[j * 1024 + w * 256], 16, 0, 0);
    }

    const int seg = t < 232 ? 0 : (t < 248 ? 1 : 2);
    const float qmax = seg == 0 ? 7.f : (seg == 1 ? 31.f : 127.f);
    int c[16];
#pragma unroll
    for (int i = 0; i < 4; ++i) {
        v4i ci = *(const v4i*)&idx[t * 16 + i * 4];
        c[i*4+0] = ci[0]; c[i*4+1] = ci[1]; c[i*4+2] = ci[2]; c[i*4+3] = ci[3];
    }
    __syncthreads();

    float v[16];
    float mx = 0.f;
#pragma unroll
    for (int i = 0; i < 16; ++i) { v[i] = rowbuf[c[i]]; mx = fmaxf(mx, fabsf(v[i])); }
    lmax[t] = mx;
    __syncthreads();
    if (w == 0) {
        float m = fmaxf(fmaxf(lmax[ln], lmax[ln + 64]), lmax[ln + 128]);
        if (ln < 40) m = fmaxf(m, lmax[ln + 192]);
#pragma unroll
        for (int off = 32; off; off >>= 1) m = fmaxf(m, __shfl_xor(m, off));
        if (ln == 0) sm[0] = m;
    } else if (w == 1) {
        float m = ln < 16 ? lmax[232 + ln] : 0.f;
#pragma unroll
        for (int off = 8; off; off >>= 1) m = fmaxf(m, __shfl_xor(m, off));
        if (ln == 0) sm[1] = m;
    } else if (w == 2) {
        float m = ln < 8 ? lmax[248 + ln] : 0.f;
#pragma unroll
        for (int off = 4; off; off >>= 1) m = fmaxf(m, __shfl_xor(m, off));
        if (ln == 0) sm[2] = m;
    }
    __syncthreads();
    float s = sm[seg] / qmax;
    if (s == 0.f) s = 1.f;
    if (t == 0 || t == 232 || t == 248) scales[seg * nrows + r] = s;
    const float rs = 1.0f / s;
    union { int8_t bb[16]; v4i q; } u;
#pragma unroll
    for (int i = 0; i < 16; ++i) {
        float qv = rintf(fminf(fmaxf(v[i] * rs, -qmax), qmax));  // RNE == np.round
        u.bb[i] = (int8_t)qv;
    }
    *(v4i*)(qout + (size_t)r * KF + t * 16) = u.q;
}

// ---------------------------------------------------------------------------
// Kernel 2 (R5-verified, byte-identical): int8 MFMA GEMM, 128x64 tile,
// grid 344, 4 waves. BK=128, 32 steps.
// A (qX, 1 MB, L2-resident): per-lane global->reg dwordx4, double-buffered.
// B (qW): global_load_lds 3-slot ring, ^(row&7) 16B-chunk swizzle.
// One wait per step: s_waitcnt vmcnt(6) lgkmcnt(0) + sched_barrier(0).
// Segment flushes after steps 28/30 (K = 3712 / 3968).
// ---------------------------------------------------------------------------
__global__ __launch_bounds__(256, 2)
void gemm_k(const int8_t* __restrict__ qX, const int8_t* __restrict__ qW,
            const float* __restrict__ sX, const float* __restrict__ sW,
            const float* __restrict__ bias, float* __restrict__ out) {
    __shared__ __align__(16) int8_t lB[3][64 * 128];

    const int bid = blockIdx.x;
    const int swz = (bid & 7) * 43 + (bid >> 3);  // 344 = 8*43: bijective
    const int row0 = (swz & 1) * 128;
    const int col0 = (swz >> 1) * 64;
    const int tid = threadIdx.x;
    const int lane = tid & 63;
    const int w = tid >> 6;
    const int lr = lane >> 3, lc = lane & 7;
    const int kg = lane >> 4;     // 0..3: K-chunk group
    const int cr = lane & 15;     // row/col within fragment

    v4i iacc[2][4];
    v4f facc[2][4];
#pragma unroll
    for (int m = 0; m < 2; ++m)
#pragma unroll
        for (int n = 0; n < 4; ++n) {
            iacc[m][n][0]=0; iacc[m][n][1]=0; iacc[m][n][2]=0; iacc[m][n][3]=0;
            facc[m][n][0]=0.f; facc[m][n][1]=0.f; facc[m][n][2]=0.f; facc[m][n][3]=0.f;
        }

    const int8_t* aRow[2];
    aRow[0] = qX + (size_t)(row0 + w * 32 + cr) * KF;
    aRow[1] = qX + (size_t)(row0 + w * 32 + 16 + cr) * KF;

    auto stageB = [&](int slot, int step) {
        const int k0 = step * 128;
        const int sc = (lc ^ lr) << 4;            // pre-swizzled source chunk
#pragma unroll
        for (int j = 0; j < 2; ++j) {
            const int brow = j * 32 + w * 8;      // +lr comes from lane offset
            const uint8_t* src = (const uint8_t*)qW + (size_t)(col0 + brow + lr) * KF + k0 + sc;
            __builtin_amdgcn_global_load_lds((gptr_t)src, (lptr_t)&lB[slot][brow * 128], 16, 0, 0);
        }
    };

    auto loadA = [&](v4i (&a)[2][2], int step) {
        const int kb = step * 128 + kg * 16;
#pragma unroll
        for (int m = 0; m < 2; ++m)
#pragma unroll
            for (int kk = 0; kk < 2; ++kk) {
                const int8_t* p = aRow[m] + kb + kk * 64;
                asm volatile("global_load_dwordx4 %0, %1, off"
                             : "=v"(a[m][kk]) : "v"(p) : "memory");
            }
    };

    auto flush = [&](int seg) {
#pragma unroll
        for (int m = 0; m < 2; ++m) {
            float sa[4];
#pragma unroll
            for (int rr = 0; rr < 4; ++rr)
                sa[rr] = sX[seg * T_ROWS + row0 + w * 32 + m * 16 + ((lane >> 4) << 2) + rr];
#pragma unroll
            for (int n = 0; n < 4; ++n) {
                const float sb = sW[seg * OF + col0 + n * 16 + (lane & 15)];
#pragma unroll
                for (int rr = 0; rr < 4; ++rr) {
                    facc[m][n][rr] += (float)iacc[m][n][rr] * (sa[rr] * sb);
                    iacc[m][n][rr] = 0;
                }
            }
        }
    };

    auto body = [&](int t, v4i (&aCur)[2][2], v4i (&aNext)[2][2]) {
        __builtin_amdgcn_s_barrier();
        // B fragments from LDS (lgkm-tracked)
        v4i bf[4][2];
        const int8_t* pb = &lB[t % 3][0];
#pragma unroll
        for (int n = 0; n < 4; ++n) {
            const int brow = n * 16 + cr;
#pragma unroll
            for (int kk = 0; kk < 2; ++kk) {
                const int ch = (kk * 4 + kg) ^ (brow & 7);
                bf[n][kk] = *(const v4i*)(pb + brow * 128 + ch * 16);
            }
        }
        // issue next prefetches (stay in flight across the wait)
        if (t + 2 < 32) stageB((t + 2) % 3, t + 2);
        if (t + 1 < 32) loadA(aNext, t + 1);
        // single wait point: aCur + B(t+1) retired; 6 newest stay in flight
        if (t < 30)       asm volatile("s_waitcnt vmcnt(6) lgkmcnt(0)" ::: "memory");
        else if (t == 30) asm volatile("s_waitcnt vmcnt(4) lgkmcnt(0)" ::: "memory");
        else              asm volatile("s_waitcnt vmcnt(0) lgkmcnt(0)" ::: "memory");
        __builtin_amdgcn_sched_barrier(0);
#pragma unroll
        for (int kk = 0; kk < 2; ++kk)
#pragma unroll
            for (int m = 0; m < 2; ++m)
#pragma unroll
                for (int n = 0; n < 4; ++n)
                    iacc[m][n] = __builtin_amdgcn_mfma_i32_16x16x64_i8(aCur[m][kk], bf[n][kk], iacc[m][n], 0, 0, 0);
        if (t == 28) flush(0);          // seg0: K [0,3712)
        else if (t == 30) flush(1);     // seg1: K [3712,3968)
    };

    v4i aA[2][2], aB[2][2];
    stageB(0, 0);
    stageB(1, 1);
    loadA(aA, 0);
    asm volatile("s_waitcnt vmcnt(6)" ::: "memory");   // B(0) landed

    for (int tt = 0; tt < 32; tt += 2) {
        body(tt,     aA, aB);
        body(tt + 1, aB, aA);
    }
    flush(2);                           // seg2: K [3968,4096)

#pragma unroll
    for (int m = 0; m < 2; ++m)
#pragma unroll
        for (int n = 0; n < 4; ++n) {
            const int colg = col0 + n * 16 + (lane & 15);
            const float bv = bias[colg];
#pragma unroll
            for (int rr = 0; rr < 4; ++rr) {
                const int rowg = row0 + w * 32 + m * 16 + ((lane >> 4) << 2) + rr;
                out[(size_t)rowg * OF + colg] = facc[m][n][rr] + bv;
            }
        }
}

// ---------------------------------------------------------------------------
// workspace layout (bytes):
//   qX     @ 0          :  1,048,576
//   qW     @ 1,048,576  : 45,088,768
//   sX     @ 46,137,344 :      3,072
//   sW     @ 46,140,416 :    132,096
// ---------------------------------------------------------------------------
extern "C" void kernel_launch(void* const* d_in, const int* in_sizes, int n_in,
                              void* d_out, int out_size, void* d_ws, size_t ws_size,
                              hipStream_t stream) {
    const float* x    = (const float*)d_in[0];
    const float* W    = (const float*)d_in[1];
    const float* bias = (const float*)d_in[2];
    const int*   ridx = (const int*)d_in[3];
    float* out = (float*)d_out;

    uint8_t* ws = (uint8_t*)d_ws;
    int8_t* qX = (int8_t*)ws;
    int8_t* qW = (int8_t*)(ws + 1048576);
    float*  sX = (float*)(ws + 46137344);
    float*  sW = (float*)(ws + 46140416);

    quant_k<<<T_ROWS + OF, 256, 0, stream>>>(x, W, ridx, qX, qW, sX, sW);
    gemm_k<<<344, 256, 0, stream>>>(qX, qW, sX, sW, bias, out);
}

// Round 15
// 73.788 us; speedup vs baseline: 17.5413x; 1.0064x over previous
//
#include <hip/hip_runtime.h>
#include <stdint.h>

#define T_ROWS 256
#define KF 4096
#define OF 11008
// grouped (dest) layout d = permuted position: [0,3712) 4-bit, [3712,3968) 6-bit,
// [3968,4096) 8-bit. Source column for dest d is simply idx[d].

typedef int   v4i __attribute__((ext_vector_type(4)));
typedef float v4f __attribute__((ext_vector_type(4)));

typedef const __attribute__((address_space(1))) uint8_t* gptr_t;
typedef __attribute__((address_space(3))) uint8_t* lptr_t;

// ---------------------------------------------------------------------------
// Kernel 1 (R14-verified, byte-identical): per-row quantize, src_of := idx.
// ---------------------------------------------------------------------------
__global__ __launch_bounds__(256) void quant_k(const float* __restrict__ x,
                                               const float* __restrict__ W,
                                               const int* __restrict__ idx,
                                               int8_t* __restrict__ qX,
                                               int8_t* __restrict__ qW,
                                               float* __restrict__ sX,
                                               float* __restrict__ sW) {
    __shared__ float rowbuf[KF];
    __shared__ float lmax[256];
    __shared__ float sm[3];
    const int b = blockIdx.x;
    const int t = threadIdx.x;
    const int w = t >> 6, ln = t & 63;
    const float* src; int8_t* qout; float* scales; int r; int nrows;
    if (b < T_ROWS) { src = x; qout = qX; scales = sX; r = b; nrows = T_ROWS; }
    else           { src = W; qout = qW; scales = sW; r = b - T_ROWS; nrows = OF; }
    const float* row = src + (size_t)r * KF;

#pragma unroll
    for (int j = 0; j < 4; ++j) {
        const uint8_t* srcp = (const uint8_t*)(row + j * 1024 + t * 4);
        __builtin_amdgcn_global_load_lds((gptr_t)srcp, (lptr_t)&rowbuf[j * 1024 + w * 256], 16, 0, 0);
    }

    const int seg = t < 232 ? 0 : (t < 248 ? 1 : 2);
    const float qmax = seg == 0 ? 7.f : (seg == 1 ? 31.f : 127.f);
    int c[16];
#pragma unroll
    for (int i = 0; i < 4; ++i) {
        v4i ci = *(const v4i*)&idx[t * 16 + i * 4];
        c[i*4+0] = ci[0]; c[i*4+1] = ci[1]; c[i*4+2] = ci[2]; c[i*4+3] = ci[3];
    }
    __syncthreads();

    float v[16];
    float mx = 0.f;
#pragma unroll
    for (int i = 0; i < 16; ++i) { v[i] = rowbuf[c[i]]; mx = fmaxf(mx, fabsf(v[i])); }
    lmax[t] = mx;
    __syncthreads();
    if (w == 0) {
        float m = fmaxf(fmaxf(lmax[ln], lmax[ln + 64]), lmax[ln + 128]);
        if (ln < 40) m = fmaxf(m, lmax[ln + 192]);
#pragma unroll
        for (int off = 32; off; off >>= 1) m = fmaxf(m, __shfl_xor(m, off));
        if (ln == 0) sm[0] = m;
    } else if (w == 1) {
        float m = ln < 16 ? lmax[232 + ln] : 0.f;
#pragma unroll
        for (int off = 8; off; off >>= 1) m = fmaxf(m, __shfl_xor(m, off));
        if (ln == 0) sm[1] = m;
    } else if (w == 2) {
        float m = ln < 8 ? lmax[248 + ln] : 0.f;
#pragma unroll
        for (int off = 4; off; off >>= 1) m = fmaxf(m, __shfl_xor(m, off));
        if (ln == 0) sm[2] = m;
    }
    __syncthreads();
    float s = sm[seg] / qmax;
    if (s == 0.f) s = 1.f;
    if (t == 0 || t == 232 || t == 248) scales[seg * nrows + r] = s;
    const float rs = 1.0f / s;
    union { int8_t bb[16]; v4i q; } u;
#pragma unroll
    for (int i = 0; i < 16; ++i) {
        float qv = rintf(fminf(fmaxf(v[i] * rs, -qmax), qmax));  // RNE == np.round
        u.bb[i] = (int8_t)qv;
    }
    *(v4i*)(qout + (size_t)r * KF + t * 16) = u.q;
}

// ---------------------------------------------------------------------------
// Kernel 2: int8 MFMA GEMM, 128x64 tile, grid 344, 4 waves, BK=128, 32 steps.
// CHANGE vs R14: depth-3 B pipeline (4-slot LDS ring) + A issued at body
// start. FIFO wait counts (loads retire in issue order):
//   steady (t<=28): keep B(t+2)[2]+A(t+1)[4]+B(t+3)[2] -> vmcnt(8),
//                   retires exactly A(t)+B(t+1).
//   t=29: vmcnt(6); t=30: vmcnt(4); t=31: vmcnt(0).
// Prologue issue order B0,B1,A0,B2 replicates steady-state history.
// ---------------------------------------------------------------------------
__global__ __launch_bounds__(256, 2)
void gemm_k(const int8_t* __restrict__ qX, const int8_t* __restrict__ qW,
            const float* __restrict__ sX, const float* __restrict__ sW,
            const float* __restrict__ bias, float* __restrict__ out) {
    __shared__ __align__(16) int8_t lB[4][64 * 128];

    const int bid = blockIdx.x;
    const int swz = (bid & 7) * 43 + (bid >> 3);  // 344 = 8*43: bijective
    const int row0 = (swz & 1) * 128;
    const int col0 = (swz >> 1) * 64;
    const int tid = threadIdx.x;
    const int lane = tid & 63;
    const int w = tid >> 6;
    const int lr = lane >> 3, lc = lane & 7;
    const int kg = lane >> 4;     // 0..3: K-chunk group
    const int cr = lane & 15;     // row/col within fragment

    v4i iacc[2][4];
    v4f facc[2][4];
#pragma unroll
    for (int m = 0; m < 2; ++m)
#pragma unroll
        for (int n = 0; n < 4; ++n) {
            iacc[m][n][0]=0; iacc[m][n][1]=0; iacc[m][n][2]=0; iacc[m][n][3]=0;
            facc[m][n][0]=0.f; facc[m][n][1]=0.f; facc[m][n][2]=0.f; facc[m][n][3]=0.f;
        }

    const int8_t* aRow[2];
    aRow[0] = qX + (size_t)(row0 + w * 32 + cr) * KF;
    aRow[1] = qX + (size_t)(row0 + w * 32 + 16 + cr) * KF;

    auto stageB = [&](int slot, int step) {
        const int k0 = step * 128;
        const int sc = (lc ^ lr) << 4;            // pre-swizzled source chunk
#pragma unroll
        for (int j = 0; j < 2; ++j) {
            const int brow = j * 32 + w * 8;      // +lr comes from lane offset
            const uint8_t* src = (const uint8_t*)qW + (size_t)(col0 + brow + lr) * KF + k0 + sc;
            __builtin_amdgcn_global_load_lds((gptr_t)src, (lptr_t)&lB[slot][brow * 128], 16, 0, 0);
        }
    };

    auto loadA = [&](v4i (&a)[2][2], int step) {
        const int kb = step * 128 + kg * 16;
#pragma unroll
        for (int m = 0; m < 2; ++m)
#pragma unroll
            for (int kk = 0; kk < 2; ++kk) {
                const int8_t* p = aRow[m] + kb + kk * 64;
                asm volatile("global_load_dwordx4 %0, %1, off"
                             : "=v"(a[m][kk]) : "v"(p) : "memory");
            }
    };

    auto flush = [&](int seg) {
#pragma unroll
        for (int m = 0; m < 2; ++m) {
            float sa[4];
#pragma unroll
            for (int rr = 0; rr < 4; ++rr)
                sa[rr] = sX[seg * T_ROWS + row0 + w * 32 + m * 16 + ((lane >> 4) << 2) + rr];
#pragma unroll
            for (int n = 0; n < 4; ++n) {
                const float sb = sW[seg * OF + col0 + n * 16 + (lane & 15)];
#pragma unroll
                for (int rr = 0; rr < 4; ++rr) {
                    facc[m][n][rr] += (float)iacc[m][n][rr] * (sa[rr] * sb);
                    iacc[m][n][rr] = 0;
                }
            }
        }
    };

    auto body = [&](int t, v4i (&aCur)[2][2], v4i (&aNext)[2][2]) {
        __builtin_amdgcn_s_barrier();
        // A prefetch first: extra latency cover before its use next body
        if (t + 1 < 32) loadA(aNext, t + 1);
        // B fragments from LDS (lgkm-tracked)
        v4i bf[4][2];
        const int8_t* pb = &lB[t & 3][0];
#pragma unroll
        for (int n = 0; n < 4; ++n) {
            const int brow = n * 16 + cr;
#pragma unroll
            for (int kk = 0; kk < 2; ++kk) {
                const int ch = (kk * 4 + kg) ^ (brow & 7);
                bf[n][kk] = *(const v4i*)(pb + brow * 128 + ch * 16);
            }
        }
        // B prefetch depth 3
        if (t + 3 < 32) stageB((t + 3) & 3, t + 3);
        // wait: retire A(t)+B(t+1); keep B(t+2)+A(t+1)+B(t+3) in flight
        if (t <= 28)      asm volatile("s_waitcnt vmcnt(8) lgkmcnt(0)" ::: "memory");
        else if (t == 29) asm volatile("s_waitcnt vmcnt(6) lgkmcnt(0)" ::: "memory");
        else if (t == 30) asm volatile("s_waitcnt vmcnt(4) lgkmcnt(0)" ::: "memory");
        else              asm volatile("s_waitcnt vmcnt(0) lgkmcnt(0)" ::: "memory");
        __builtin_amdgcn_sched_barrier(0);
#pragma unroll
        for (int kk = 0; kk < 2; ++kk)
#pragma unroll
            for (int m = 0; m < 2; ++m)
#pragma unroll
                for (int n = 0; n < 4; ++n)
                    iacc[m][n] = __builtin_amdgcn_mfma_i32_16x16x64_i8(aCur[m][kk], bf[n][kk], iacc[m][n], 0, 0, 0);
        if (t == 28) flush(0);          // seg0: K [0,3712)
        else if (t == 30) flush(1);     // seg1: K [3712,3968)
    };

    v4i aA[2][2], aB[2][2];
    // prologue order B0,B1,A0,B2 — replicates steady-state FIFO history
    stageB(0, 0);
    stageB(1, 1);
    loadA(aA, 0);
    stageB(2, 2);
    asm volatile("s_waitcnt vmcnt(8)" ::: "memory");   // B(0) landed

    for (int tt = 0; tt < 32; tt += 2) {
        body(tt,     aA, aB);
        body(tt + 1, aB, aA);
    }
    flush(2);                           // seg2: K [3968,4096)

#pragma unroll
    for (int m = 0; m < 2; ++m)
#pragma unroll
        for (int n = 0; n < 4; ++n) {
            const int colg = col0 + n * 16 + (lane & 15);
            const float bv = bias[colg];
#pragma unroll
            for (int rr = 0; rr < 4; ++rr) {
                const int rowg = row0 + w * 32 + m * 16 + ((lane >> 4) << 2) + rr;
                out[(size_t)rowg * OF + colg] = facc[m][n][rr] + bv;
            }
        }
}

// ---------------------------------------------------------------------------
// workspace layout (bytes):
//   qX     @ 0          :  1,048,576
//   qW     @ 1,048,576  : 45,088,768
//   sX     @ 46,137,344 :      3,072
//   sW     @ 46,140,416 :    132,096
// ---------------------------------------------------------------------------
extern "C" void kernel_launch(void* const* d_in, const int* in_sizes, int n_in,
                              void* d_out, int out_size, void* d_ws, size_t ws_size,
                              hipStream_t stream) {
    const float* x    = (const float*)d_in[0];
    const float* W    = (const float*)d_in[1];
    const float* bias = (const float*)d_in[2];
    const int*   ridx = (const int*)d_in[3];
    float* out = (float*)d_out;

    uint8_t* ws = (uint8_t*)d_ws;
    int8_t* qX = (int8_t*)ws;
    int8_t* qW = (int8_t*)(ws + 1048576);
    float*  sX = (float*)(ws + 46137344);
    float*  sW = (float*)(ws + 46140416);

    quant_k<<<T_ROWS + OF, 256, 0, stream>>>(x, W, ridx, qX, qW, sX, sW);
    gemm_k<<<344, 256, 0, stream>>>(qX, qW, sX, sW, bias, out);
}

// Round 16
// 68.381 us; speedup vs baseline: 18.9282x; 1.0791x over previous
//
#include <hip/hip_runtime.h>
#include <stdint.h>

#define T_ROWS 256
#define KF 4096
#define OF 11008
// grouped (dest) layout d = permuted position: [0,3712) 4-bit, [3712,3968) 6-bit,
// [3968,4096) 8-bit. Source column for dest d is simply idx[d].

typedef int   v4i __attribute__((ext_vector_type(4)));
typedef float v4f __attribute__((ext_vector_type(4)));

typedef const __attribute__((address_space(1))) uint8_t* gptr_t;
typedef __attribute__((address_space(3))) uint8_t* lptr_t;

// ---------------------------------------------------------------------------
// Kernel 1 (R14-verified, byte-identical): per-row quantize, src_of := idx.
// ---------------------------------------------------------------------------
__global__ __launch_bounds__(256) void quant_k(const float* __restrict__ x,
                                               const float* __restrict__ W,
                                               const int* __restrict__ idx,
                                               int8_t* __restrict__ qX,
                                               int8_t* __restrict__ qW,
                                               float* __restrict__ sX,
                                               float* __restrict__ sW) {
    __shared__ float rowbuf[KF];
    __shared__ float lmax[256];
    __shared__ float sm[3];
    const int b = blockIdx.x;
    const int t = threadIdx.x;
    const int w = t >> 6, ln = t & 63;
    const float* src; int8_t* qout; float* scales; int r; int nrows;
    if (b < T_ROWS) { src = x; qout = qX; scales = sX; r = b; nrows = T_ROWS; }
    else           { src = W; qout = qW; scales = sW; r = b - T_ROWS; nrows = OF; }
    const float* row = src + (size_t)r * KF;

#pragma unroll
    for (int j = 0; j < 4; ++j) {
        const uint8_t* srcp = (const uint8_t*)(row + j * 1024 + t * 4);
        __builtin_amdgcn_global_load_lds((gptr_t)srcp, (lptr_t)&rowbuf[j * 1024 + w * 256], 16, 0, 0);
    }

    const int seg = t < 232 ? 0 : (t < 248 ? 1 : 2);
    const float qmax = seg == 0 ? 7.f : (seg == 1 ? 31.f : 127.f);
    int c[16];
#pragma unroll
    for (int i = 0; i < 4; ++i) {
        v4i ci = *(const v4i*)&idx[t * 16 + i * 4];
        c[i*4+0] = ci[0]; c[i*4+1] = ci[1]; c[i*4+2] = ci[2]; c[i*4+3] = ci[3];
    }
    __syncthreads();

    float v[16];
    float mx = 0.f;
#pragma unroll
    for (int i = 0; i < 16; ++i) { v[i] = rowbuf[c[i]]; mx = fmaxf(mx, fabsf(v[i])); }
    lmax[t] = mx;
    __syncthreads();
    if (w == 0) {
        float m = fmaxf(fmaxf(lmax[ln], lmax[ln + 64]), lmax[ln + 128]);
        if (ln < 40) m = fmaxf(m, lmax[ln + 192]);
#pragma unroll
        for (int off = 32; off; off >>= 1) m = fmaxf(m, __shfl_xor(m, off));
        if (ln == 0) sm[0] = m;
    } else if (w == 1) {
        float m = ln < 16 ? lmax[232 + ln] : 0.f;
#pragma unroll
        for (int off = 8; off; off >>= 1) m = fmaxf(m, __shfl_xor(m, off));
        if (ln == 0) sm[1] = m;
    } else if (w == 2) {
        float m = ln < 8 ? lmax[248 + ln] : 0.f;
#pragma unroll
        for (int off = 4; off; off >>= 1) m = fmaxf(m, __shfl_xor(m, off));
        if (ln == 0) sm[2] = m;
    }
    __syncthreads();
    float s = sm[seg] / qmax;
    if (s == 0.f) s = 1.f;
    if (t == 0 || t == 232 || t == 248) scales[seg * nrows + r] = s;
    const float rs = 1.0f / s;
    union { int8_t bb[16]; v4i q; } u;
#pragma unroll
    for (int i = 0; i < 16; ++i) {
        float qv = rintf(fminf(fmaxf(v[i] * rs, -qmax), qmax));  // RNE == np.round
        u.bb[i] = (int8_t)qv;
    }
    *(v4i*)(qout + (size_t)r * KF + t * 16) = u.q;
}

// ---------------------------------------------------------------------------
// Kernel 2: int8 MFMA GEMM, 64x64 tile, grid 688 (= 8 XCDs x 86), 4 waves,
// BK=128, 32 steps. CHANGE vs R15: balanced grid (2.69 avg / 3 max blocks/CU
// vs 2/1.34) and mb = swz&3 so the 4 row-tiles sharing a B panel run adjacent
// on the same XCD (panel fetched ~once per XCD).
// Per wave: 16x64 output (1x4 fragments). A: 2 per-lane dwordx4/step.
// B: 4-slot LDS ring, ^(row&7) chunk swizzle, depth-3 prefetch.
// FIFO waits: steady vmcnt(6) (keep B(t+2)[2]+A(t+1)[2]+B(t+3)[2]);
// t=29: 4; t=30: 2; t=31: 0. Prologue B0,B1,A0,B2.
// ---------------------------------------------------------------------------
__global__ __launch_bounds__(256, 3)
void gemm_k(const int8_t* __restrict__ qX, const int8_t* __restrict__ qW,
            const float* __restrict__ sX, const float* __restrict__ sW,
            const float* __restrict__ bias, float* __restrict__ out) {
    __shared__ __align__(16) int8_t lB[4][64 * 128];

    const int bid = blockIdx.x;
    const int swz = (bid & 7) * 86 + (bid >> 3);  // 688 = 8*86: bijective
    const int row0 = (swz & 3) * 64;
    const int col0 = (swz >> 2) * 64;
    const int tid = threadIdx.x;
    const int lane = tid & 63;
    const int w = tid >> 6;
    const int lr = lane >> 3, lc = lane & 7;
    const int kg = lane >> 4;     // 0..3: K-chunk group
    const int cr = lane & 15;     // row/col within fragment

    v4i iacc[4];
    v4f facc[4];
#pragma unroll
    for (int n = 0; n < 4; ++n) {
        iacc[n][0]=0; iacc[n][1]=0; iacc[n][2]=0; iacc[n][3]=0;
        facc[n][0]=0.f; facc[n][1]=0.f; facc[n][2]=0.f; facc[n][3]=0.f;
    }

    const int8_t* aRow = qX + (size_t)(row0 + w * 16 + cr) * KF;

    auto stageB = [&](int slot, int step) {
        const int k0 = step * 128;
        const int sc = (lc ^ lr) << 4;            // pre-swizzled source chunk
#pragma unroll
        for (int j = 0; j < 2; ++j) {
            const int brow = j * 32 + w * 8;      // +lr comes from lane offset
            const uint8_t* src = (const uint8_t*)qW + (size_t)(col0 + brow + lr) * KF + k0 + sc;
            __builtin_amdgcn_global_load_lds((gptr_t)src, (lptr_t)&lB[slot][brow * 128], 16, 0, 0);
        }
    };

    auto loadA = [&](v4i (&a)[2], int step) {
        const int kb = step * 128 + kg * 16;
#pragma unroll
        for (int kk = 0; kk < 2; ++kk) {
            const int8_t* p = aRow + kb + kk * 64;
            asm volatile("global_load_dwordx4 %0, %1, off"
                         : "=v"(a[kk]) : "v"(p) : "memory");
        }
    };

    auto flush = [&](int seg) {
        float sa[4];
#pragma unroll
        for (int rr = 0; rr < 4; ++rr)
            sa[rr] = sX[seg * T_ROWS + row0 + w * 16 + ((lane >> 4) << 2) + rr];
#pragma unroll
        for (int n = 0; n < 4; ++n) {
            const float sb = sW[seg * OF + col0 + n * 16 + (lane & 15)];
#pragma unroll
            for (int rr = 0; rr < 4; ++rr) {
                facc[n][rr] += (float)iacc[n][rr] * (sa[rr] * sb);
                iacc[n][rr] = 0;
            }
        }
    };

    auto body = [&](int t, v4i (&aCur)[2], v4i (&aNext)[2]) {
        __builtin_amdgcn_s_barrier();
        // A prefetch first (latency cover until next body)
        if (t + 1 < 32) loadA(aNext, t + 1);
        // B fragments from LDS (lgkm-tracked)
        v4i bf[4][2];
        const int8_t* pb = &lB[t & 3][0];
#pragma unroll
        for (int n = 0; n < 4; ++n) {
            const int brow = n * 16 + cr;
#pragma unroll
            for (int kk = 0; kk < 2; ++kk) {
                const int ch = (kk * 4 + kg) ^ (brow & 7);
                bf[n][kk] = *(const v4i*)(pb + brow * 128 + ch * 16);
            }
        }
        // B prefetch depth 3
        if (t + 3 < 32) stageB((t + 3) & 3, t + 3);
        // wait: retire B(t+1)+A(t); keep B(t+2)+A(t+1)+B(t+3)
        if (t <= 28)      asm volatile("s_waitcnt vmcnt(6) lgkmcnt(0)" ::: "memory");
        else if (t == 29) asm volatile("s_waitcnt vmcnt(4) lgkmcnt(0)" ::: "memory");
        else if (t == 30) asm volatile("s_waitcnt vmcnt(2) lgkmcnt(0)" ::: "memory");
        else              asm volatile("s_waitcnt vmcnt(0) lgkmcnt(0)" ::: "memory");
        __builtin_amdgcn_sched_barrier(0);
#pragma unroll
        for (int kk = 0; kk < 2; ++kk)
#pragma unroll
            for (int n = 0; n < 4; ++n)
                iacc[n] = __builtin_amdgcn_mfma_i32_16x16x64_i8(aCur[kk], bf[n][kk], iacc[n], 0, 0, 0);
        if (t == 28) flush(0);          // seg0: K [0,3712)
        else if (t == 30) flush(1);     // seg1: K [3712,3968)
    };

    v4i aA[2], aB[2];
    // prologue order B0,B1,A0,B2 — replicates steady-state FIFO history
    stageB(0, 0);
    stageB(1, 1);
    loadA(aA, 0);
    stageB(2, 2);
    asm volatile("s_waitcnt vmcnt(6)" ::: "memory");   // B(0) landed

    for (int tt = 0; tt < 32; tt += 2) {
        body(tt,     aA, aB);
        body(tt + 1, aB, aA);
    }
    flush(2);                           // seg2: K [3968,4096)

#pragma unroll
    for (int n = 0; n < 4; ++n) {
        const int colg = col0 + n * 16 + (lane & 15);
        const float bv = bias[colg];
#pragma unroll
        for (int rr = 0; rr < 4; ++rr) {
            const int rowg = row0 + w * 16 + ((lane >> 4) << 2) + rr;
            out[(size_t)rowg * OF + colg] = facc[n][rr] + bv;
        }
    }
}

// ---------------------------------------------------------------------------
// workspace layout (bytes):
//   qX     @ 0          :  1,048,576
//   qW     @ 1,048,576  : 45,088,768
//   sX     @ 46,137,344 :      3,072
//   sW     @ 46,140,416 :    132,096
// ---------------------------------------------------------------------------
extern "C" void kernel_launch(void* const* d_in, const int* in_sizes, int n_in,
                              void* d_out, int out_size, void* d_ws, size_t ws_size,
                              hipStream_t stream) {
    const float* x    = (const float*)d_in[0];
    const float* W    = (const float*)d_in[1];
    const float* bias = (const float*)d_in[2];
    const int*   ridx = (const int*)d_in[3];
    float* out = (float*)d_out;

    uint8_t* ws = (uint8_t*)d_ws;
    int8_t* qX = (int8_t*)ws;
    int8_t* qW = (int8_t*)(ws + 1048576);
    float*  sX = (float*)(ws + 46137344);
    float*  sW = (float*)(ws + 46140416);

    quant_k<<<T_ROWS + OF, 256, 0, stream>>>(x, W, ridx, qX, qW, sX, sW);
    gemm_k<<<688, 256, 0, stream>>>(qX, qW, sX, sW, bias, out);
}